// Round 1
// baseline (87.180 us; speedup 1.0000x reference)
//
#include <hip/hip_runtime.h>

// LIFSpike forward scan: x [B,N,T] fp32, Vth [N], tau [N] -> out [B,N,T] fp32
// u_{t} = tau*(u_{t-1} - Vth*o_{t-1}) + x_t ; o_t = (u_t - Vth > 0) ? 1 : 0
// Sequential over T=64 only; one thread per (b,n) sequence, T contiguous.

constexpr int B = 128;
constexpr int N = 4096;
constexpr int T = 64;

__global__ __launch_bounds__(256) void lif_spike_kernel(
    const float* __restrict__ x,
    const float* __restrict__ Vth,
    const float* __restrict__ tau,
    float* __restrict__ out)
{
    const long long idx = (long long)blockIdx.x * blockDim.x + threadIdx.x; // over B*N
    const int n = (int)(idx & (N - 1));

    // constrain_method == 'forward'
    const float vth = fmaxf(Vth[n], 0.0f);
    const float tc  = fminf(fmaxf(tau[n], 0.0f), 1.0f);

    const float4* __restrict__ xp = reinterpret_cast<const float4*>(x + idx * T);
    float4* __restrict__ op       = reinterpret_cast<float4*>(out + idx * T);

    // Preload full sequence: 16 outstanding dwordx4 loads (latency hiding).
    float4 xv[T / 4];
    #pragma unroll
    for (int j = 0; j < T / 4; ++j) xv[j] = xp[j];

    float u = 0.0f;
    float o = 0.0f;
    #pragma unroll
    for (int j = 0; j < T / 4; ++j) {
        float xs0 = xv[j].x, xs1 = xv[j].y, xs2 = xv[j].z, xs3 = xv[j].w;
        float4 r;

        u = tc * (u - vth * o) + xs0;
        o = (u > vth) ? 1.0f : 0.0f;
        r.x = o;

        u = tc * (u - vth * o) + xs1;
        o = (u > vth) ? 1.0f : 0.0f;
        r.y = o;

        u = tc * (u - vth * o) + xs2;
        o = (u > vth) ? 1.0f : 0.0f;
        r.z = o;

        u = tc * (u - vth * o) + xs3;
        o = (u > vth) ? 1.0f : 0.0f;
        r.w = o;

        op[j] = r;
    }
}

extern "C" void kernel_launch(void* const* d_in, const int* in_sizes, int n_in,
                              void* d_out, int out_size, void* d_ws, size_t ws_size,
                              hipStream_t stream) {
    const float* x   = (const float*)d_in[0];
    const float* Vth = (const float*)d_in[1];
    const float* tau = (const float*)d_in[2];
    float* out       = (float*)d_out;

    const int total = B * N;          // 524288 threads, one per sequence
    const int block = 256;
    const int grid  = total / block;  // 2048 blocks

    lif_spike_kernel<<<grid, block, 0, stream>>>(x, Vth, tau, out);
}

// Round 2
// 48.876 us; speedup vs baseline: 1.7837x; 1.7837x over previous
//
#include <hip/hip_runtime.h>

// LIFSpike forward scan: x [B,N,T] fp32, Vth [N], tau [N] -> out [B,N,T] fp32
// u_t = tau*(u_{t-1} - Vth*o_{t-1}) + x_t ; o_t = (u_t - Vth > 0) ? 1 : 0
//
// Strategy: full coalescing via LDS tile. Block of 256 threads owns 256
// contiguous sequences (rows) of T=64 floats = 64 KB.
//   Phase A: coalesced global->LDS (XOR-swizzled rows, conflict-free)
//   Phase B: per-thread in-place scan of its row inside LDS
//   Phase C: coalesced LDS->global stores (full-line writes, no RMW)

constexpr int B = 128;
constexpr int N = 4096;
constexpr int T = 64;
constexpr int ROWS = 256;             // rows (sequences) per block
constexpr int TILE_WORDS = ROWS * T;  // 16384 words = 64 KB

__global__ __launch_bounds__(256) void lif_spike_kernel(
    const float* __restrict__ x,
    const float* __restrict__ Vth,
    const float* __restrict__ tau,
    float* __restrict__ out)
{
    __shared__ float lds[TILE_WORDS];  // 64 KB

    const int tid = threadIdx.x;
    const long long tile_base = (long long)blockIdx.x * TILE_WORDS;

    // ---- Phase A: coalesced global -> LDS (swizzled) ----
    // iteration k: wave reads 256 consecutive words -> 256B/instr coalesced
    #pragma unroll
    for (int k = 0; k < 64; ++k) {
        const int widx = k * 256 + tid;      // word index within tile
        const int row  = widx >> 6;          // k*4 + (tid>>6)
        const int t    = widx & 63;          // tid & 63
        lds[(row << 6) | (t ^ (row & 31))] = x[tile_base + widx];
    }
    __syncthreads();

    // ---- Phase B: scan own row in LDS (conflict-free via XOR swizzle) ----
    {
        const long long grow = (long long)blockIdx.x * ROWS + tid;  // global row
        const int n = (int)(grow & (N - 1));

        const float vth = fmaxf(Vth[n], 0.0f);             // constrain 'forward'
        const float tc  = fminf(fmaxf(tau[n], 0.0f), 1.0f);

        float u = 0.0f, o = 0.0f;
        const int base = tid << 6;
        const int c    = tid & 31;
        #pragma unroll
        for (int t = 0; t < 64; ++t) {
            const int idx = base | (t ^ c);
            const float xt = lds[idx];
            u = tc * (u - vth * o) + xt;
            o = (u > vth) ? 1.0f : 0.0f;
            lds[idx] = o;   // in-place: same thread owns the row
        }
    }
    __syncthreads();

    // ---- Phase C: coalesced LDS -> global (full-line writes) ----
    #pragma unroll
    for (int k = 0; k < 64; ++k) {
        const int widx = k * 256 + tid;
        const int row  = widx >> 6;
        const int t    = widx & 63;
        out[tile_base + widx] = lds[(row << 6) | (t ^ (row & 31))];
    }
}

extern "C" void kernel_launch(void* const* d_in, const int* in_sizes, int n_in,
                              void* d_out, int out_size, void* d_ws, size_t ws_size,
                              hipStream_t stream) {
    const float* x   = (const float*)d_in[0];
    const float* Vth = (const float*)d_in[1];
    const float* tau = (const float*)d_in[2];
    float* out       = (float*)d_out;

    const int grid = (B * N) / ROWS;  // 2048 blocks
    lif_spike_kernel<<<grid, 256, 0, stream>>>(x, Vth, tau, out);
}